// Round 6
// baseline (604.912 us; speedup 1.0000x reference)
//
#include <hip/hip_runtime.h>
#include <math.h>

// Problem constants
#define NPIX   131072      // 32*64*64 pixels
#define KCODES 512
#define DIM    64
#define HW     4096        // 64*64
#define CHW    262144      // 64*4096
#define NBLK   2048        // 64 px per block

// Output layout (floats, concatenated in reference return order)
#define O_Q    1ll
#define O_PERP 8388609ll
#define O_ENC  8388610ll
#define O_IDX  75497474ll

// ws layout (floats): [0] loss accum, [1..512] counts (u32), [513..1024] esq,
//                     [1280..34047] embT[64][512] (16B-aligned base)
#define WS_EMBT 1280

// Replicate numpy pairwise_sum of x**2 for n=64 (8 accs, stride-8, pairwise combine).
__device__ __forceinline__ float np_sumsq64(const float (&x)[64]) {
#pragma clang fp contract(off)
  float r0 = x[0]*x[0], r1 = x[1]*x[1], r2 = x[2]*x[2], r3 = x[3]*x[3];
  float r4 = x[4]*x[4], r5 = x[5]*x[5], r6 = x[6]*x[6], r7 = x[7]*x[7];
#pragma unroll
  for (int i = 8; i < 64; i += 8) {
    r0 += x[i+0]*x[i+0];
    r1 += x[i+1]*x[i+1];
    r2 += x[i+2]*x[i+2];
    r3 += x[i+3]*x[i+3];
    r4 += x[i+4]*x[i+4];
    r5 += x[i+5]*x[i+5];
    r6 += x[i+6]*x[i+6];
    r7 += x[i+7]*x[i+7];
  }
  return ((r0+r1)+(r2+r3))+((r4+r5)+(r6+r7));
}

// Prep: zero loss+counts, esq[k] (np-pairwise), and embT[64][512] transpose.
__global__ void vq_prep(const float* __restrict__ emb, float* __restrict__ ws) {
  const int t = threadIdx.x;  // 512 threads = one code each
  if (t == 0) ws[0] = 0.0f;
  ((unsigned*)ws)[1 + t] = 0u;
  float x[64];
  const float* e = emb + t * DIM;
#pragma unroll
  for (int d = 0; d < 64; ++d) x[d] = e[d];
  ws[513 + t] = np_sumsq64(x);
  // embT[d][k] = emb[k][d]; stores coalesced across t per d.
#pragma unroll
  for (int d = 0; d < 64; ++d) ws[WS_EMBT + d * 512 + t] = x[d];
}

__device__ __forceinline__ void dist_phase(int Hh, int ci, int pi,
                                           const float (&acc)[8][8],
                                           const float* __restrict__ esq_l,
                                           const float* __restrict__ zsq_l,
                                           float (&bd)[8], int (&bk)[8]) {
  // ascending (q,r) = ascending k; strict < == np.argmin semantics.
#pragma unroll
  for (int q = 0; q < 2; ++q)
#pragma unroll
    for (int r = 0; r < 4; ++r) {
      const int k = 256 * Hh + 128 * q + 4 * ci + r;
      const float eq = esq_l[k];
#pragma unroll
      for (int j = 0; j < 8; ++j) {
        const float dist = (zsq_l[8 * pi + j] + eq) - 2.0f * acc[j][4 * q + r];
        if (dist < bd[j]) { bd[j] = dist; bk[j] = k; }
      }
    }
}

// Main: round-13 barrier-free main loop via pre-transposed embT in ws.
// Post-mortems: r0-r4 structures were barrier/lockstep-bound (VALU<50%, LDS
// ~25%, vmem low — nothing saturated; LDS pipe is only ~41us, NOT the cap as
// r5 assumed). r5's remap added 8.5M bank conflicts (32B/lane stride) and
// thrashed L1 with 128KB/block emb reads -> 215us. This round removes the
// REASON for in-loop barriers: the e-operand is read directly from a
// pre-transposed embT[64][512] in ws (written once by vq_prep). Two float4
// loads per dl, lane-stride 16B, coalesced; all resident waves walk the same
// 2KB rows -> L1/L2-hot. LDS holds only the 16KB z tile (+esq) = ~19KB;
// z reads keep the r1 conflict-free pattern (half-wave broadcast, 16B
// stride). Barriers per block: 2 at the top (z publish, zsq publish), then
// the whole 2x64-dl FMA loop runs with ZERO barriers — waves and the 4
// resident blocks/CU slide freely, e-loads pipeline with nothing to drain.
// Block = 256 threads (4 waves), 64 px, grid 2048 = 2 exact rounds at
// 4 blocks/CU (VGPR-capped 4 waves/SIMD via launch_bounds; LDS would allow 8).
// Enc zeros stream as NT stores in 8 batches inside the loop; quantized NT.
// Exactness (bit-identical to all passing rounds): per-(px,k) single fmaf
// chain d=0..63 ascending; dist=(zsq+esq)-2*acc; ascending-(q,r) scan per
// half (k ascending), strict <; ci-group butterfly tie-break to lower k;
// np_sumsq64 for zsq/esq.
__global__ __launch_bounds__(256, 4)
void vq_main(
    const float* __restrict__ z, const float* __restrict__ emb,
    float* __restrict__ out, float* __restrict__ ws)
{
  __shared__ float z_l[64 * 64];     // 16KB: z_l[d][px]
  __shared__ float esq_l[512];
  __shared__ float zsq_l[64];
  __shared__ int   ridx_l[64];
  __shared__ float wsum[4];

  const int t   = threadIdx.x;       // 0..255
  const int ci  = t & 31;
  const int pi  = t >> 5;            // 0..7
  const int blk = blockIdx.x;        // grid = 2048
  const int n0  = blk * 64;          // 64 consecutive pixels (same batch b)
  const int b   = n0 >> 12;
  const int hw0 = n0 & 4095;
  const float* zg   = z + (size_t)b * CHW + hw0;
  const float* embT = ws + WS_EMBT;  // [64][512], 16B-aligned

  esq_l[t]       = ws[513 + t];
  esq_l[t + 256] = ws[769 + t];

  // Stage z_l[d][px]: 64 rows of 64 floats (coalesced float4 global reads).
  {
    const int i     = t & 15;        // float4 index within row
    const int dbase = t >> 4;        // 0..15
#pragma unroll
    for (int r = 0; r < 4; ++r) {
      const int d = dbase + 16 * r;
      *(float4*)&z_l[d * 64 + 4 * i] = *(const float4*)(zg + (size_t)d * HW + 4 * i);
    }
  }
  __syncthreads();   // B0: z_l, esq_l ready

  // Exact per-pixel zsq (np pairwise pattern), one thread per pixel.
  if (t < 64) {
    float x[64];
#pragma unroll
    for (int d = 0; d < 64; ++d) x[d] = z_l[d * 64 + t];
    zsq_l[t] = np_sumsq64(x);
  }
  __syncthreads();   // B1: zsq_l published. NO MORE barriers until epilogue.

  float bd[8];
  int   bk[8];
#pragma unroll
  for (int j = 0; j < 8; ++j) { bd[j] = INFINITY; bk[j] = 0; }

  double* encd = (double*)(out + O_ENC) + (size_t)n0 * 256;  // 8B-aligned

  for (int H = 0; H < 2; ++H) {
    const float* eTH = embT + 256 * H + 4 * ci;
    float acc[8][8];
#pragma unroll
    for (int j = 0; j < 8; ++j)
#pragma unroll
      for (int c = 0; c < 8; ++c) acc[j][c] = 0.0f;

    for (int ds = 0; ds < 4; ++ds) {
      // One batch (16KB/block) of encoding zeros; NT so the 268MB stream
      // doesn't evict embT/z from L2. Drained by the pre-epilogue barrier.
      {
        const int batch = 4 * H + ds;
#pragma unroll
        for (int u = 0; u < 8; ++u)
          __builtin_nontemporal_store(0.0, encd + (size_t)batch * 2048 + u * 256 + t);
      }
#pragma unroll
      for (int dq = 0; dq < 16; ++dq) {
        const int dl = 16 * ds + dq;
        // e operand: straight from global embT row (L1/L2-hot, coalesced).
        const float4 e0 = *(const float4*)(eTH + dl * 512);        // q=0 codes
        const float4 e1 = *(const float4*)(eTH + dl * 512 + 128);  // q=1 codes
        // z operand: conflict-free LDS (half-wave broadcast, 16B stride).
        const float* zp = &z_l[dl * 64 + 8 * pi];
        const float4 za0 = *(const float4*)(zp + 0);
        const float4 za1 = *(const float4*)(zp + 4);
        const float zr[8] = {za0.x, za0.y, za0.z, za0.w,
                             za1.x, za1.y, za1.z, za1.w};
        const float er[8] = {e0.x, e0.y, e0.z, e0.w,
                             e1.x, e1.y, e1.z, e1.w};
#pragma unroll
        for (int j = 0; j < 8; ++j)
#pragma unroll
          for (int c = 0; c < 8; ++c)
            acc[j][c] = fmaf(zr[j], er[c], acc[j][c]);
      }
    }
    dist_phase(H, ci, pi, acc, esq_l, zsq_l, bd, bk);
  }

  // Butterfly merge across the 32 ci-lanes (tie-break: lower k), exact.
#pragma unroll
  for (int m = 16; m >= 1; m >>= 1) {
#pragma unroll
    for (int j = 0; j < 8; ++j) {
      const float od = __shfl_xor(bd[j], m, 64);
      const int   ok = __shfl_xor(bk[j], m, 64);
      if (od < bd[j] || (od == bd[j] && ok < bk[j])) { bd[j] = od; bk[j] = ok; }
    }
  }
  if (ci == 0) {
#pragma unroll
    for (int j = 0; j < 8; ++j) ridx_l[8 * pi + j] = bk[j];
  }
  __syncthreads();  // publishes ridx_l; per-wave vmcnt(0) drains enc zeros

  // ---- epilogue (all 4 waves) ----
  if (t < 64) {
    const int k = ridx_l[t];
    out[O_IDX + n0 + t] = (float)k;
    atomicAdd((unsigned*)ws + 1 + k, 1u);
    // One-hot scatter: zero at this slot is already globally complete.
    out[O_ENC + (size_t)(n0 + t) * 512 + k] = 1.0f;
  }

  // quantized (transposed back to [B,C,H,W]) + loss, distributed: thread
  // (px = t&63, dq = t>>6) handles 16 d's of one pixel; NT stores coalesced.
  {
    const int px = t & 63;
    const int dq = t >> 6;
    const int k  = ridx_l[px];
    const float* e0 = emb + ((size_t)k << 6);
    float* q0 = out + O_Q + (size_t)b * CHW + hw0 + px;
    float lsum = 0.0f;
#pragma unroll
    for (int j = 0; j < 16; ++j) {
      const int d = dq * 16 + j;
      const float ev = e0[d];
      const float df = ev - z_l[d * 64 + px];
      lsum = fmaf(df, df, lsum);
      __builtin_nontemporal_store(ev, q0 + (size_t)d * HW);
    }
#pragma unroll
    for (int off = 32; off > 0; off >>= 1) lsum += __shfl_down(lsum, off, 64);
    if ((t & 63) == 0) wsum[t >> 6] = lsum;
  }
  __syncthreads();
  if (t == 0) atomicAdd(ws, (wsum[0] + wsum[1]) + (wsum[2] + wsum[3]));
}

// Finalize: perplexity from counts (exact: counts/2^17), loss mean.
__global__ void vq_fin(float* __restrict__ out, const float* __restrict__ ws) {
  __shared__ float red[8];
  const int t = threadIdx.x;  // 512
  const unsigned* counts = (const unsigned*)ws + 1;
  const float p = (float)counts[t] * (1.0f / 131072.0f);
  float h = p * logf(p + 1e-10f);
#pragma unroll
  for (int off = 32; off > 0; off >>= 1) h += __shfl_down(h, off, 64);
  if ((t & 63) == 0) red[t >> 6] = h;
  __syncthreads();
  if (t == 0) {
    float H = 0.0f;
#pragma unroll
    for (int w = 0; w < 8; ++w) H += red[w];
    out[O_PERP] = expf(-H);
    out[0] = 1.25f * ws[0] * (1.0f / 8388608.0f);
  }
}

extern "C" void kernel_launch(void* const* d_in, const int* in_sizes, int n_in,
                              void* d_out, int out_size, void* d_ws, size_t ws_size,
                              hipStream_t stream) {
  const float* z   = (const float*)d_in[0];
  const float* emb = (const float*)d_in[1];
  float* out = (float*)d_out;
  float* ws  = (float*)d_ws;

  vq_prep<<<1, 512, 0, stream>>>(emb, ws);
  vq_main<<<NBLK, 256, 0, stream>>>(z, emb, out, ws);
  vq_fin<<<1, 512, 0, stream>>>(out, ws);
}

// Round 7
// 433.456 us; speedup vs baseline: 1.3956x; 1.3956x over previous
//
#include <hip/hip_runtime.h>
#include <math.h>

// Problem constants
#define NPIX   131072      // 32*64*64 pixels
#define KCODES 512
#define DIM    64
#define HW     4096        // 64*64
#define CHW    262144      // 64*4096
#define NBLK   1024        // 128 px per block

// Output layout (floats, concatenated in reference return order)
#define O_Q    1ll
#define O_PERP 8388609ll
#define O_ENC  8388610ll
#define O_IDX  75497474ll

// ws layout (floats): [0] loss accum, [1..512] counts (u32), [513..1024] esq,
//                     [1280..34047] embT[64][512]
#define WS_EMBT 1280

// global->LDS direct load: 16B per lane, deposit = ldsbase + lane*16.
#define GLD16(gp, lp) __builtin_amdgcn_global_load_lds( \
    (const __attribute__((address_space(1))) unsigned int*)(gp), \
    (__attribute__((address_space(3))) unsigned int*)(lp), 16, 0, 0)

// Replicate numpy pairwise_sum of x**2 for n=64 (8 accs, stride-8, pairwise combine).
__device__ __forceinline__ float np_sumsq64(const float (&x)[64]) {
#pragma clang fp contract(off)
  float r0 = x[0]*x[0], r1 = x[1]*x[1], r2 = x[2]*x[2], r3 = x[3]*x[3];
  float r4 = x[4]*x[4], r5 = x[5]*x[5], r6 = x[6]*x[6], r7 = x[7]*x[7];
#pragma unroll
  for (int i = 8; i < 64; i += 8) {
    r0 += x[i+0]*x[i+0];
    r1 += x[i+1]*x[i+1];
    r2 += x[i+2]*x[i+2];
    r3 += x[i+3]*x[i+3];
    r4 += x[i+4]*x[i+4];
    r5 += x[i+5]*x[i+5];
    r6 += x[i+6]*x[i+6];
    r7 += x[i+7]*x[i+7];
  }
  return ((r0+r1)+(r2+r3))+((r4+r5)+(r6+r7));
}

// Prep: zero loss+counts, esq[k] (np-pairwise), embT[64][512] transpose.
__global__ void vq_prep(const float* __restrict__ emb, float* __restrict__ ws) {
  const int t = threadIdx.x;  // 512 threads = one code each
  if (t == 0) ws[0] = 0.0f;
  ((unsigned*)ws)[1 + t] = 0u;
  float x[64];
  const float* e = emb + t * DIM;
#pragma unroll
  for (int d = 0; d < 64; ++d) x[d] = e[d];
  ws[513 + t] = np_sumsq64(x);
  // embT[d][k] = emb[k][d]; stores coalesced across t per d.
#pragma unroll
  for (int d = 0; d < 64; ++d) ws[WS_EMBT + d * 512 + t] = x[d];
}

// --- inlined helpers ---

// Issue slice g's 16 [dl][256] rows into dstbuf via global_load_lds.
// Wave wv covers rows 2wv, 2wv+1; each call = 1KB (one row), coalesced, and
// deposits linearly in lane order -> exactly the r1-proven LDS layout.
__device__ __forceinline__ void issue_ET(const float* __restrict__ embT,
                                         float* __restrict__ dstbuf,
                                         int g, int wv, int lane) {
#pragma unroll
  for (int q = 0; q < 2; ++q) {
    const int r = 2 * wv + q;  // dl row 0..15
    const float* gp = embT + (size_t)((g & 3) * 16 + r) * 512
                    + 256 * (g >> 2) + 4 * lane;
    GLD16(gp, dstbuf + r * 256);
  }
}

__device__ __forceinline__ void enc_zero(float2* __restrict__ encb, int g, int t) {
  const float2 zz = make_float2(0.0f, 0.0f);
#pragma unroll
  for (int u = 0; u < 8; ++u)
    encb[(size_t)g * 4096 + u * 512 + t] = zz;
}

__device__ __forceinline__ void dl_loop(const float* __restrict__ ETb,
                                        const float* __restrict__ zl,
                                        int sdim, int pi, int ci,
                                        float (&acc)[8][8]) {
#pragma unroll 2
  for (int dl = 0; dl < 16; ++dl) {
    const float* zp = &zl[(sdim + dl) * 128 + 8 * pi];
    const float4 za0 = *(const float4*)(zp + 0);
    const float4 za1 = *(const float4*)(zp + 4);
    const float* ep = &ETb[dl * 256 + 4 * ci];
    const float4 e0 = *(const float4*)(ep + 0);     // codes 256H+4ci+0..3
    const float4 e1 = *(const float4*)(ep + 128);   // codes 256H+128+4ci..
    const float zr[8] = {za0.x, za0.y, za0.z, za0.w,
                         za1.x, za1.y, za1.z, za1.w};
    const float er_[8] = {e0.x, e0.y, e0.z, e0.w,
                          e1.x, e1.y, e1.z, e1.w};
#pragma unroll
    for (int j = 0; j < 8; ++j)
#pragma unroll
      for (int c = 0; c < 8; ++c)
        acc[j][c] = fmaf(zr[j], er_[c], acc[j][c]);
  }
}

__device__ __forceinline__ void dist_phase(int Hh, int ci, int pi,
                                           const float (&acc)[8][8],
                                           const float* __restrict__ esq_l,
                                           const float* __restrict__ zsq_l,
                                           float (&bd)[8], int (&bk)[8]) {
  // ascending (q,r) = ascending k; strict < == np.argmin semantics.
#pragma unroll
  for (int q = 0; q < 2; ++q)
#pragma unroll
    for (int r = 0; r < 4; ++r) {
      const int k = 256 * Hh + 128 * q + 4 * ci + r;
      const float eq = esq_l[k];
#pragma unroll
      for (int j = 0; j < 8; ++j) {
        const float dist = (zsq_l[8 * pi + j] + eq) - 2.0f * acc[j][4 * q + r];
        if (dist < bd[j]) { bd[j] = dist; bk[j] = k; }
      }
    }
}

// Main: round-14 = r1 structure + global_load_lds staging + zero-cost ET
// double-buffer (9 barriers) + setprio around the FMA burst.
// r6 post-mortem: NT stores amplified WRITE to 1045MB and evicted embT from
// L2 (FETCH 328MB) -> ALL stores regular again (r0/r1 kept FETCH ~84MB).
// r1 pipe budget: VALU ~80us, LDS ~82us, HBM ~84us, measured 175 -> overlap
// problem. This round cuts schedule overhead without touching operand paths:
//  (a) z and ET staged via __builtin_amdgcn_global_load_lds (16B): no VGPR
//      round-trip, ET slice = 2 instr/wave (was 4 loads + 16 ds_writes + 16
//      temp regs), z stage = 4 instr/wave. LDS layouts byte-identical to
//      r1's proven conflict-free ones.
//  (b) ET double-buffer at zero reg cost: top of slice g issues loads for
//      slice g+1 into buf[(g+1)&1] (last read in slice g-1, separated by
//      barrier g-1); barrier g's vmcnt(0) drains them. 16 -> 9 barriers,
//      load latency hidden under the 2000+cy FMA phase.
//  (c) s_setprio(1) around dl_loop (T5): 2 resident blocks are phase-offset
//      -> scheduler favors the FMA-issuing wave.
// ET source = pre-transposed embT[64][512] in ws (vq_prep); rows re-read
// per block stay L2-hot with regular stores.
// Exactness: per-(px,k) single fmaf chain d=0..63 ascending; dist =
// (zsq+esq)-2*acc; ascending-(q,r) scan (k ascending), strict <; ci-group
// butterfly tie-break to lower k; np_sumsq64 for zsq/esq -> bit-identical.
__global__ __launch_bounds__(512, 4)
void vq_main(
    const float* __restrict__ z, const float* __restrict__ emb,
    float* __restrict__ out, float* __restrict__ ws)
{
  __shared__ float ET_s[2][16 * 256];  // 32KB: double-buffered 16-d ET slices
  __shared__ float z_l[64 * 128];      // 32KB: z_l[d][px]
  __shared__ float esq_l[512];
  __shared__ float zsq_l[128];
  __shared__ int   ridx_l[128];
  __shared__ float wsum[8];

  const int t    = threadIdx.x;      // 0..511
  const int lane = t & 63;
  const int wv   = t >> 6;           // 0..7
  const int ci   = t & 31;
  const int pi   = t >> 5;           // 0..15
  const int blk  = blockIdx.x;       // grid = 1024
  const int n0   = blk * 128;        // 128 consecutive pixels (same batch b)
  const int b    = n0 >> 12;
  const int hw0  = n0 & 4095;
  const float* zg   = z + (size_t)b * CHW + hw0;
  const float* embT = ws + WS_EMBT;  // [64][512]

  esq_l[t] = ws[513 + t];

  // Stage z_l[d][px] via global_load_lds: 4 calls/wave, each 1KB = two
  // 128-float rows; per-lane global addr = row d0+(lane>>5), px 4*(lane&31).
#pragma unroll
  for (int c = 0; c < 4; ++c) {
    const int d0 = 2 * (4 * wv + c);
    const float* gp = zg + (size_t)(d0 + (lane >> 5)) * HW + 4 * (lane & 31);
    GLD16(gp, &z_l[d0 * 128]);
  }

  issue_ET(embT, &ET_s[0][0], 0, wv, lane);   // slice 0 -> buf0

  __syncthreads();   // B0: z_l, esq_l, ET0 ready (vmcnt+lgkm drained)

  // Exact per-pixel zsq (np pairwise pattern), one thread per pixel.
  // Published by the barrier at end of slice 0 (consumed at slice 3).
  if (t < 128) {
    float x[64];
#pragma unroll
    for (int d = 0; d < 64; ++d) x[d] = z_l[d * 128 + t];
    zsq_l[t] = np_sumsq64(x);
  }

  float bd[8];
  int   bk[8];
#pragma unroll
  for (int j = 0; j < 8; ++j) { bd[j] = INFINITY; bk[j] = 0; }
  float acc[8][8];
#pragma unroll
  for (int j = 0; j < 8; ++j)
#pragma unroll
    for (int c = 0; c < 8; ++c) acc[j][c] = 0.0f;

  float2* encb = (float2*)(out + O_ENC) + (size_t)n0 * 256;  // 8B-aligned

  // Main loop: slices g=0..7 (H = g>>2, dim-slice = g&3), 1 barrier each.
  // Hazards: issue(g+1)->buf[(g+1)&1] happens after barrier(g-1) (that
  // buffer's reads ended in slice g-1); barrier(g) drains the loads before
  // slice g+1 reads them. Reads of buf[g&1] end before barrier(g); its next
  // overwrite is issued at top of slice g+1, after barrier(g).
  for (int g = 0; g < 8; ++g) {
    if (g < 7) issue_ET(embT, &ET_s[(g + 1) & 1][0], g + 1, wv, lane);
    enc_zero(encb, g, t);   // regular stores; drained by this slice's barrier
    __builtin_amdgcn_s_setprio(1);
    dl_loop(&ET_s[g & 1][0], z_l, 16 * (g & 3), pi, ci, acc);
    __builtin_amdgcn_s_setprio(0);
    if ((g & 3) == 3) {     // g==3 (H0) / g==7 (H1); zsq_l published since B(0)
      dist_phase(g >> 2, ci, pi, acc, esq_l, zsq_l, bd, bk);
      if (g == 3) {
#pragma unroll
        for (int j = 0; j < 8; ++j)
#pragma unroll
          for (int c = 0; c < 8; ++c) acc[j][c] = 0.0f;
      }
    }
    __syncthreads();
  }

  // Butterfly merge across the 32 ci-lanes (tie-break: lower k), exact.
#pragma unroll
  for (int m = 16; m >= 1; m >>= 1) {
#pragma unroll
    for (int j = 0; j < 8; ++j) {
      const float od = __shfl_xor(bd[j], m, 64);
      const int   ok = __shfl_xor(bk[j], m, 64);
      if (od < bd[j] || (od == bd[j] && ok < bk[j])) { bd[j] = od; bk[j] = ok; }
    }
  }
  if (ci == 0) {
#pragma unroll
    for (int j = 0; j < 8; ++j) ridx_l[8 * pi + j] = bk[j];
  }
  __syncthreads();  // publishes ridx_l (enc zeros drained at loop barriers)

  // ---- epilogue (all 8 waves) ----
  if (t < 128) {
    const int k = ridx_l[t];
    out[O_IDX + n0 + t] = (float)k;
    atomicAdd((unsigned*)ws + 1 + k, 1u);
    // One-hot scatter: zero at this slot is already globally complete.
    out[O_ENC + (size_t)(n0 + t) * 512 + k] = 1.0f;
  }

  // quantized (transposed back to [B,C,H,W]) + loss, distributed: thread
  // (px = t&127, dq = t>>7) handles 16 d's of one pixel; stores coalesced.
  {
    const int px = t & 127;
    const int dq = t >> 7;
    const int k  = ridx_l[px];
    const float* e0 = emb + ((size_t)k << 6);
    float* q0 = out + O_Q + (size_t)b * CHW + hw0 + px;
    float lsum = 0.0f;
#pragma unroll
    for (int j = 0; j < 16; ++j) {
      const int d = dq * 16 + j;
      const float ev = e0[d];
      const float df = ev - z_l[d * 128 + px];
      lsum = fmaf(df, df, lsum);
      q0[(size_t)d * HW] = ev;
    }
#pragma unroll
    for (int off = 32; off > 0; off >>= 1) lsum += __shfl_down(lsum, off, 64);
    if ((t & 63) == 0) wsum[t >> 6] = lsum;
  }
  __syncthreads();
  if (t == 0)
    atomicAdd(ws, ((wsum[0] + wsum[1]) + (wsum[2] + wsum[3])) +
                  ((wsum[4] + wsum[5]) + (wsum[6] + wsum[7])));
}

// Finalize: perplexity from counts (exact: counts/2^17), loss mean.
__global__ void vq_fin(float* __restrict__ out, const float* __restrict__ ws) {
  __shared__ float red[8];
  const int t = threadIdx.x;  // 512
  const unsigned* counts = (const unsigned*)ws + 1;
  const float p = (float)counts[t] * (1.0f / 131072.0f);
  float h = p * logf(p + 1e-10f);
#pragma unroll
  for (int off = 32; off > 0; off >>= 1) h += __shfl_down(h, off, 64);
  if ((t & 63) == 0) red[t >> 6] = h;
  __syncthreads();
  if (t == 0) {
    float H = 0.0f;
#pragma unroll
    for (int w = 0; w < 8; ++w) H += red[w];
    out[O_PERP] = expf(-H);
    out[0] = 1.25f * ws[0] * (1.0f / 8388608.0f);
  }
}

extern "C" void kernel_launch(void* const* d_in, const int* in_sizes, int n_in,
                              void* d_out, int out_size, void* d_ws, size_t ws_size,
                              hipStream_t stream) {
  const float* z   = (const float*)d_in[0];
  const float* emb = (const float*)d_in[1];
  float* out = (float*)d_out;
  float* ws  = (float*)d_ws;

  vq_prep<<<1, 512, 0, stream>>>(emb, ws);
  vq_main<<<NBLK, 512, 0, stream>>>(z, emb, out, ws);
  vq_fin<<<1, 512, 0, stream>>>(out, ws);
}